// Round 3
// baseline (319.454 us; speedup 1.0000x reference)
//
#include <hip/hip_runtime.h>
#include <hip/hip_cooperative_groups.h>
#include <stdint.h>

namespace cg = cooperative_groups;

// Problem constants (fixed by setup_inputs): B=8, T=4096, D=H=512
#define NB 8
#define NT 4096
#define ND 512
#define NH 512
#define NN 1024        // 2H
#define NM (NB * NT)   // 32768 GEMM rows
#define NK 512         // GEMM K = D
#define NCH 128        // scan chunks along T
#define CTS 32         // steps per chunk (NCH*CTS == NT)

typedef __bf16 bf16x8 __attribute__((ext_vector_type(8)));
typedef float floatx4 __attribute__((ext_vector_type(4)));
typedef unsigned int uint_g __attribute__((address_space(1)));
typedef unsigned int uint_l __attribute__((address_space(3)));

__device__ __forceinline__ float bf2f(unsigned short u) {
    union { unsigned int i; float f; } v; v.i = ((unsigned int)u) << 16; return v.f;
}
__device__ __forceinline__ unsigned short f2bf(float f) {
    union { float f; unsigned int i; } v; v.f = f;
    return (unsigned short)((v.i + 0x7FFFu + ((v.i >> 16) & 1u)) >> 16);
}

// async 16B global->LDS; HW writes lane i at (wave-uniform base) + i*16
__device__ __forceinline__ void load_lds16(const void* g, void* l) {
    __builtin_amdgcn_global_load_lds((const uint_g*)g, (uint_l*)l, 16, 0, 0);
}

// ---------------- Kernel 1: LayerNorm -> xn (bf16), one wave per row -------
__global__ __launch_bounds__(256) void ln_kernel(const float* __restrict__ x,
                                                 const float* __restrict__ gamma,
                                                 const float* __restrict__ beta,
                                                 unsigned short* __restrict__ xn) {
    int wid = threadIdx.x >> 6, lane = threadIdx.x & 63;
    size_t row = (size_t)blockIdx.x * 4 + wid;
    const float4* xr = (const float4*)(x + row * ND);
    float4 v0 = xr[lane];
    float4 v1 = xr[lane + 64];
    float s  = (v0.x + v0.y) + (v0.z + v0.w) + (v1.x + v1.y) + (v1.z + v1.w);
    float sq = v0.x * v0.x + v0.y * v0.y + v0.z * v0.z + v0.w * v0.w
             + v1.x * v1.x + v1.y * v1.y + v1.z * v1.z + v1.w * v1.w;
#pragma unroll
    for (int off = 32; off > 0; off >>= 1) {
        s  += __shfl_xor(s,  off, 64);
        sq += __shfl_xor(sq, off, 64);
    }
    float mu   = s * (1.0f / ND);
    float var  = sq * (1.0f / ND) - mu * mu;
    float rstd = rsqrtf(var + 1e-10f);
    const float4* gr = (const float4*)gamma;
    const float4* br = (const float4*)beta;
    float4 g0 = gr[lane], g1 = gr[lane + 64];
    float4 b0 = br[lane], b1 = br[lane + 64];
    ushort4 o0, o1;
    o0.x = f2bf((v0.x - mu) * rstd * g0.x + b0.x);
    o0.y = f2bf((v0.y - mu) * rstd * g0.y + b0.y);
    o0.z = f2bf((v0.z - mu) * rstd * g0.z + b0.z);
    o0.w = f2bf((v0.w - mu) * rstd * g0.w + b0.w);
    o1.x = f2bf((v1.x - mu) * rstd * g1.x + b1.x);
    o1.y = f2bf((v1.y - mu) * rstd * g1.y + b1.y);
    o1.z = f2bf((v1.z - mu) * rstd * g1.z + b1.z);
    o1.w = f2bf((v1.w - mu) * rstd * g1.w + b1.w);
    ushort4* xo = (ushort4*)(xn + row * ND);
    xo[lane]      = o0;
    xo[lane + 64] = o1;
}

// ---------------- Kernel 2: W (K x N) -> Wt (N x K) bf16 ----------------
__global__ __launch_bounds__(256) void wt_kernel(const float* __restrict__ W,
                                                 unsigned short* __restrict__ Wt) {
    __shared__ float tile[32][33];
    int n0 = blockIdx.x * 32;
    int k0 = blockIdx.y * 32;
    int tx = threadIdx.x, ty = threadIdx.y;  // 32 x 8
#pragma unroll
    for (int j = 0; j < 4; ++j)
        tile[ty + j * 8][tx] = W[(size_t)(k0 + ty + j * 8) * NN + n0 + tx];
    __syncthreads();
#pragma unroll
    for (int j = 0; j < 4; ++j)
        Wt[(size_t)(n0 + ty + j * 8) * NK + k0 + tx] = f2bf(tile[tx][ty + j * 8]);
}

// ---------------- Kernel 3: GEMM gh = xn @ W  (bf16 MFMA, fp32 acc) -------
// A: xn [NM x NK] bf16 row-major; Bt: Wt [NN x NK] bf16 row-major (K contig)
// C: gh [NM x NN] bf16. Tile 128x128, BK=64, 4 waves (2x2), wave = 64x64.
// Block order: mt fastest (round-1 measured 57.5us / 53MB FETCH; nt-fast
// regressed to 64us / 132MB because A-tile sharers land on different XCDs).
__global__ __launch_bounds__(256) void gemm_kernel(const unsigned short* __restrict__ A,
                                                   const unsigned short* __restrict__ Bt,
                                                   unsigned short* __restrict__ C) {
    __shared__ __align__(16) unsigned short As[128 * 64];
    __shared__ __align__(16) unsigned short Bs[128 * 64];
    int tid  = threadIdx.x;
    int lane = tid & 63;
    int wid  = tid >> 6;
    int wm = wid & 1, wn = wid >> 1;
    int bx = blockIdx.x;
    int mt = bx & 255;   // 256 M-tiles
    int nt = bx >> 8;    // 8 N-tiles
    const int Rm = mt * 128, Rn = nt * 128;

    // staging lane decomposition: 64 lanes = 8 rows x 8 chunks(16B)
    int rloc = lane >> 3;          // row within 8-row group
    int cl   = lane & 7;           // LDS chunk slot
    int cg   = cl ^ rloc;          // global chunk (XOR swizzle)

    int frow = lane & 15;          // MFMA m/n index
    int quad = lane >> 4;          // MFMA k-group
    int fx   = lane & 7;           // swizzle key for frag reads

    floatx4 acc[4][4];
#pragma unroll
    for (int i = 0; i < 4; ++i)
#pragma unroll
        for (int j = 0; j < 4; ++j)
            acc[i][j] = (floatx4){0.f, 0.f, 0.f, 0.f};

#pragma unroll 1
    for (int kt = 0; kt < NK / 64; ++kt) {
        int k0 = kt * 64;
        __syncthreads();  // previous tile fully consumed
#pragma unroll
        for (int s = 0; s < 4; ++s) {
            int g  = wid * 4 + s;      // 16 groups of 8 rows
            int ml = g * 8 + rloc;
            load_lds16(A + (size_t)(Rm + ml) * NK + k0 + cg * 8, As + g * 512);
        }
#pragma unroll
        for (int s = 0; s < 4; ++s) {
            int g  = wid * 4 + s;
            int nl = g * 8 + rloc;
            load_lds16(Bt + (size_t)(Rn + nl) * NK + k0 + cg * 8, Bs + g * 512);
        }
        __syncthreads();  // compiler drains vmcnt(0) before barrier
#pragma unroll
        for (int ks = 0; ks < 2; ++ks) {
            int ch = (ks * 4 + quad) ^ fx;
            bf16x8 af[4], bfr[4];
#pragma unroll
            for (int mi = 0; mi < 4; ++mi) {
                int ml = wm * 64 + mi * 16 + frow;
                af[mi] = *(const bf16x8*)(As + ml * 64 + ch * 8);
            }
#pragma unroll
            for (int ni = 0; ni < 4; ++ni) {
                int nl = wn * 64 + ni * 16 + frow;
                bfr[ni] = *(const bf16x8*)(Bs + nl * 64 + ch * 8);
            }
#pragma unroll
            for (int mi = 0; mi < 4; ++mi)
#pragma unroll
                for (int ni = 0; ni < 4; ++ni)
                    acc[mi][ni] = __builtin_amdgcn_mfma_f32_16x16x32_bf16(
                        af[mi], bfr[ni], acc[mi][ni], 0, 0, 0);
        }
    }
    // epilogue: C/D layout col=lane&15, row=quad*4+reg
#pragma unroll
    for (int mi = 0; mi < 4; ++mi)
#pragma unroll
        for (int ni = 0; ni < 4; ++ni)
#pragma unroll
            for (int r = 0; r < 4; ++r) {
                int row = Rm + wm * 64 + mi * 16 + quad * 4 + r;
                int col = Rn + wn * 64 + ni * 16 + frow;
                C[(size_t)row * NN + col] = f2bf(acc[mi][ni][r]);
            }
}

// gate math: h_t = a*h + z*g(hpre), a=sigmoid(-k), z=sigmoid(k)
__device__ __forceinline__ void gate_av(unsigned short ku, unsigned short pu,
                                        float& a, float& v) {
    float k = bf2f(ku), p = bf2f(pu);
    float e = __expf(k);
    a = __builtin_amdgcn_rcpf(1.0f + e);
    float z = e * a;  // sigmoid(k)
    float gneg = __builtin_amdgcn_rcpf(1.0f + __expf(-p));
    float g = (p >= 0.0f) ? (p + 0.5f) : gneg;
    v = z * g;
}

// ---------------- Kernel 4: fused single-pass scan (cooperative) ----------
// Phase 1: per-chunk (A,V) aggregates -> cA/cV [b][c][NH] (chunk-major)
// grid.sync()
// Phase 2: each block composes exclusive prefix over its predecessors
//          (h0 = 0, so only hv = a*hv + v is needed; cA/cV are 4MB, L3-hot)
// Phase 3: replay own chunk (gh slice L2-warm), out = h + x, write hidden.
__global__ __launch_bounds__(128) void scan_fused(const unsigned short* __restrict__ gh,
                                                  const float* __restrict__ x,
                                                  float* __restrict__ out,
                                                  float* __restrict__ hidden,
                                                  float* __restrict__ cA,
                                                  float* __restrict__ cV) {
    int b = blockIdx.x >> 7, c = blockIdx.x & 127;
    int h = threadIdx.x * 4;
    size_t row0 = (size_t)(b * NT + c * CTS);
    const unsigned short* base = gh + row0 * NN;

    // ---- Phase 1: chunk aggregate ----
    float A0 = 1.f, A1 = 1.f, A2 = 1.f, A3 = 1.f;
    float V0 = 0.f, V1 = 0.f, V2 = 0.f, V3 = 0.f;
#pragma unroll 8
    for (int t = 0; t < CTS; ++t) {
        const unsigned short* p = base + (size_t)t * NN;
        ushort4 kk = *(const ushort4*)(p + h);
        ushort4 hh = *(const ushort4*)(p + NH + h);
        float a, v;
        gate_av(kk.x, hh.x, a, v); V0 = a * V0 + v; A0 *= a;
        gate_av(kk.y, hh.y, a, v); V1 = a * V1 + v; A1 *= a;
        gate_av(kk.z, hh.z, a, v); V2 = a * V2 + v; A2 *= a;
        gate_av(kk.w, hh.w, a, v); V3 = a * V3 + v; A3 *= a;
    }
    size_t o = (size_t)blockIdx.x * NH + h;
    *(float4*)(cA + o) = make_float4(A0, A1, A2, A3);
    *(float4*)(cV + o) = make_float4(V0, V1, V2, V3);

    cg::this_grid().sync();

    // ---- Phase 2: exclusive prefix for this chunk's channels ----
    float4 hv = make_float4(0.f, 0.f, 0.f, 0.f);
    const float* ap = cA + ((size_t)b * NCH) * NH + h;
    const float* vp = cV + ((size_t)b * NCH) * NH + h;
#pragma unroll 4
    for (int pch = 0; pch < c; ++pch) {
        float4 a = *(const float4*)(ap + (size_t)pch * NH);
        float4 v = *(const float4*)(vp + (size_t)pch * NH);
        hv.x = a.x * hv.x + v.x;
        hv.y = a.y * hv.y + v.y;
        hv.z = a.z * hv.z + v.z;
        hv.w = a.w * hv.w + v.w;
    }

    // ---- Phase 3: replay & write ----
    const float* xb = x + row0 * ND;
    float* ob = out + row0 * ND;
#pragma unroll 8
    for (int t = 0; t < CTS; ++t) {
        const unsigned short* p = base + (size_t)t * NN;
        ushort4 kk = *(const ushort4*)(p + h);
        ushort4 hh = *(const ushort4*)(p + NH + h);
        float a, v;
        gate_av(kk.x, hh.x, a, v); hv.x = a * hv.x + v;
        gate_av(kk.y, hh.y, a, v); hv.y = a * hv.y + v;
        gate_av(kk.z, hh.z, a, v); hv.z = a * hv.z + v;
        gate_av(kk.w, hh.w, a, v); hv.w = a * hv.w + v;
        float4 xv = *(const float4*)(xb + (size_t)t * ND + h);
        float4 ov;
        ov.x = hv.x + xv.x; ov.y = hv.y + xv.y;
        ov.z = hv.z + xv.z; ov.w = hv.w + xv.w;
        *(float4*)(ob + (size_t)t * ND + h) = ov;
    }
    if (c == NCH - 1)
        *(float4*)(hidden + (size_t)b * NH + h) = hv;
}

extern "C" void kernel_launch(void* const* d_in, const int* in_sizes, int n_in,
                              void* d_out, int out_size, void* d_ws, size_t ws_size,
                              hipStream_t stream) {
    const float* x     = (const float*)d_in[0];
    const float* gamma = (const float*)d_in[1];
    const float* beta  = (const float*)d_in[2];
    const float* W     = (const float*)d_in[3];

    float* out    = (float*)d_out;
    float* hidden = out + (size_t)NM * ND;

    // ws layout: Wt(1MB) | gh(64MB) | cA(2MB) | cV(2MB) = 69MB
    char* ws = (char*)d_ws;
    unsigned short* Wt = (unsigned short*)ws;
    unsigned short* gh = (unsigned short*)(ws + (size_t)(1u << 20));
    float* cA = (float*)(ws + (size_t)(1u << 20) + (size_t)NM * NN * 2);
    float* cV = cA + (size_t)NB * NCH * NH;
    // xn scratch lives in d_out (dead before scan_fused overwrites the region)
    unsigned short* xn = (unsigned short*)d_out;

    wt_kernel<<<dim3(32, 16), dim3(32, 8), 0, stream>>>(W, Wt);
    ln_kernel<<<NM / 4, 256, 0, stream>>>(x, gamma, beta, xn);
    gemm_kernel<<<2048, 256, 0, stream>>>(xn, Wt, gh);

    const unsigned short* ghp = gh;
    const float* xp = x;
    float* outp = out;
    float* hiddenp = hidden;
    float* cAp = cA;
    float* cVp = cV;
    void* args[] = {(void*)&ghp, (void*)&xp, (void*)&outp,
                    (void*)&hiddenp, (void*)&cAp, (void*)&cVp};
    hipLaunchCooperativeKernel((void*)scan_fused, dim3(NB * NCH), dim3(128),
                               args, 0, stream);
}

// Round 4
// 215.834 us; speedup vs baseline: 1.4801x; 1.4801x over previous
//
#include <hip/hip_runtime.h>
#include <stdint.h>

// Problem constants (fixed by setup_inputs): B=8, T=4096, D=H=512
#define NB 8
#define NT 4096
#define ND 512
#define NH 512
#define NN 1024        // 2H
#define NM (NB * NT)   // 32768 GEMM rows
#define NK 512         // GEMM K = D
#define NCH 128        // scan chunks along T
#define CTS 32         // steps per chunk (NCH*CTS == NT)

typedef __bf16 bf16x8 __attribute__((ext_vector_type(8)));
typedef float floatx4 __attribute__((ext_vector_type(4)));
typedef unsigned int uint_g __attribute__((address_space(1)));
typedef unsigned int uint_l __attribute__((address_space(3)));

__device__ __forceinline__ float bf2f(unsigned short u) {
    union { unsigned int i; float f; } v; v.i = ((unsigned int)u) << 16; return v.f;
}
__device__ __forceinline__ unsigned short f2bf(float f) {
    union { float f; unsigned int i; } v; v.f = f;
    return (unsigned short)((v.i + 0x7FFFu + ((v.i >> 16) & 1u)) >> 16);
}

// async 16B global->LDS; HW writes lane i at (wave-uniform base) + i*16
__device__ __forceinline__ void load_lds16(const void* g, void* l) {
    __builtin_amdgcn_global_load_lds((const uint_g*)g, (uint_l*)l, 16, 0, 0);
}

// ------- Kernel 1: prep = Wt transpose (blocks 0..511) + LayerNorm --------
__global__ __launch_bounds__(256) void prep_kernel(const float* __restrict__ x,
                                                   const float* __restrict__ gamma,
                                                   const float* __restrict__ beta,
                                                   const float* __restrict__ W,
                                                   unsigned short* __restrict__ xn,
                                                   unsigned short* __restrict__ Wt) {
    if (blockIdx.x < 512) {
        // W (K x N) -> Wt (N x K) bf16, 32x32 tile
        __shared__ float tile[32][33];
        int bid = blockIdx.x;
        int n0 = (bid & 31) * 32;
        int k0 = (bid >> 5) * 32;
        int tx = threadIdx.x & 31, ty = threadIdx.x >> 5;  // 32 x 8
#pragma unroll
        for (int j = 0; j < 4; ++j)
            tile[ty + j * 8][tx] = W[(size_t)(k0 + ty + j * 8) * NN + n0 + tx];
        __syncthreads();
#pragma unroll
        for (int j = 0; j < 4; ++j)
            Wt[(size_t)(n0 + ty + j * 8) * NK + k0 + tx] = f2bf(tile[tx][ty + j * 8]);
        return;
    }
    // LayerNorm: one wave per row
    int wid = threadIdx.x >> 6, lane = threadIdx.x & 63;
    size_t row = (size_t)(blockIdx.x - 512) * 4 + wid;
    const float4* xr = (const float4*)(x + row * ND);
    float4 v0 = xr[lane];
    float4 v1 = xr[lane + 64];
    float s  = (v0.x + v0.y) + (v0.z + v0.w) + (v1.x + v1.y) + (v1.z + v1.w);
    float sq = v0.x * v0.x + v0.y * v0.y + v0.z * v0.z + v0.w * v0.w
             + v1.x * v1.x + v1.y * v1.y + v1.z * v1.z + v1.w * v1.w;
#pragma unroll
    for (int off = 32; off > 0; off >>= 1) {
        s  += __shfl_xor(s,  off, 64);
        sq += __shfl_xor(sq, off, 64);
    }
    float mu   = s * (1.0f / ND);
    float var  = sq * (1.0f / ND) - mu * mu;
    float rstd = rsqrtf(var + 1e-10f);
    const float4* gr = (const float4*)gamma;
    const float4* br = (const float4*)beta;
    float4 g0 = gr[lane], g1 = gr[lane + 64];
    float4 b0 = br[lane], b1 = br[lane + 64];
    ushort4 o0, o1;
    o0.x = f2bf((v0.x - mu) * rstd * g0.x + b0.x);
    o0.y = f2bf((v0.y - mu) * rstd * g0.y + b0.y);
    o0.z = f2bf((v0.z - mu) * rstd * g0.z + b0.z);
    o0.w = f2bf((v0.w - mu) * rstd * g0.w + b0.w);
    o1.x = f2bf((v1.x - mu) * rstd * g1.x + b1.x);
    o1.y = f2bf((v1.y - mu) * rstd * g1.y + b1.y);
    o1.z = f2bf((v1.z - mu) * rstd * g1.z + b1.z);
    o1.w = f2bf((v1.w - mu) * rstd * g1.w + b1.w);
    ushort4* xo = (ushort4*)(xn + row * ND);
    xo[lane]      = o0;
    xo[lane + 64] = o1;
}

// ---------------- Kernel 2: GEMM gh = xn @ W  (bf16 MFMA, fp32 acc) -------
// A: xn [NM x NK] bf16 row-major; Bt: Wt [NN x NK] bf16 row-major (K contig)
// C: gh [NM x NN] bf16. Tile 128x128, BK=64, 4 waves (2x2), wave = 64x64.
// Block order: mt fastest (round-1 measured 57.5us / 53MB FETCH; nt-fast
// regressed to 64us / 132MB because A-tile sharers land on different XCDs).
__global__ __launch_bounds__(256) void gemm_kernel(const unsigned short* __restrict__ A,
                                                   const unsigned short* __restrict__ Bt,
                                                   unsigned short* __restrict__ C) {
    __shared__ __align__(16) unsigned short As[128 * 64];
    __shared__ __align__(16) unsigned short Bs[128 * 64];
    int tid  = threadIdx.x;
    int lane = tid & 63;
    int wid  = tid >> 6;
    int wm = wid & 1, wn = wid >> 1;
    int bx = blockIdx.x;
    int mt = bx & 255;   // 256 M-tiles
    int nt = bx >> 8;    // 8 N-tiles
    const int Rm = mt * 128, Rn = nt * 128;

    // staging lane decomposition: 64 lanes = 8 rows x 8 chunks(16B)
    int rloc = lane >> 3;          // row within 8-row group
    int cl   = lane & 7;           // LDS chunk slot
    int cg   = cl ^ rloc;          // global chunk (XOR swizzle)

    int frow = lane & 15;          // MFMA m/n index
    int quad = lane >> 4;          // MFMA k-group
    int fx   = lane & 7;           // swizzle key for frag reads

    floatx4 acc[4][4];
#pragma unroll
    for (int i = 0; i < 4; ++i)
#pragma unroll
        for (int j = 0; j < 4; ++j)
            acc[i][j] = (floatx4){0.f, 0.f, 0.f, 0.f};

#pragma unroll 1
    for (int kt = 0; kt < NK / 64; ++kt) {
        int k0 = kt * 64;
        __syncthreads();  // previous tile fully consumed
#pragma unroll
        for (int s = 0; s < 4; ++s) {
            int g  = wid * 4 + s;      // 16 groups of 8 rows
            int ml = g * 8 + rloc;
            load_lds16(A + (size_t)(Rm + ml) * NK + k0 + cg * 8, As + g * 512);
        }
#pragma unroll
        for (int s = 0; s < 4; ++s) {
            int g  = wid * 4 + s;
            int nl = g * 8 + rloc;
            load_lds16(Bt + (size_t)(Rn + nl) * NK + k0 + cg * 8, Bs + g * 512);
        }
        __syncthreads();  // compiler drains vmcnt(0) before barrier
#pragma unroll
        for (int ks = 0; ks < 2; ++ks) {
            int ch = (ks * 4 + quad) ^ fx;
            bf16x8 af[4], bfr[4];
#pragma unroll
            for (int mi = 0; mi < 4; ++mi) {
                int ml = wm * 64 + mi * 16 + frow;
                af[mi] = *(const bf16x8*)(As + ml * 64 + ch * 8);
            }
#pragma unroll
            for (int ni = 0; ni < 4; ++ni) {
                int nl = wn * 64 + ni * 16 + frow;
                bfr[ni] = *(const bf16x8*)(Bs + nl * 64 + ch * 8);
            }
#pragma unroll
            for (int mi = 0; mi < 4; ++mi)
#pragma unroll
                for (int ni = 0; ni < 4; ++ni)
                    acc[mi][ni] = __builtin_amdgcn_mfma_f32_16x16x32_bf16(
                        af[mi], bfr[ni], acc[mi][ni], 0, 0, 0);
        }
    }
    // epilogue: C/D layout col=lane&15, row=quad*4+reg
#pragma unroll
    for (int mi = 0; mi < 4; ++mi)
#pragma unroll
        for (int ni = 0; ni < 4; ++ni)
#pragma unroll
            for (int r = 0; r < 4; ++r) {
                int row = Rm + wm * 64 + mi * 16 + quad * 4 + r;
                int col = Rn + wn * 64 + ni * 16 + frow;
                C[(size_t)row * NN + col] = f2bf(acc[mi][ni][r]);
            }
}

// gate math: h_t = a*h + z*g(hpre), a=sigmoid(-k), z=sigmoid(k)
__device__ __forceinline__ void gate_av(unsigned short ku, unsigned short pu,
                                        float& a, float& v) {
    float k = bf2f(ku), p = bf2f(pu);
    float e = __expf(k);
    a = __builtin_amdgcn_rcpf(1.0f + e);
    float z = e * a;  // sigmoid(k)
    float gneg = __builtin_amdgcn_rcpf(1.0f + __expf(-p));
    float g = (p >= 0.0f) ? (p + 0.5f) : gneg;
    v = z * g;
}

// ---------------- Kernel 3: per-chunk scan aggregates ----------------
// 128-thread blocks, 1 chunk per block, 4 channels per thread.
// Explicit 8-deep load batching: 16 loads in flight per wave (8KB) to cover
// ~900-cycle HBM latency (round-3's VGPR=36 showed compiler kept only ~2).
// cA/cV layout: [b][h][c] (channel-major) so scan2 reads coalesce.
__global__ __launch_bounds__(128) void scan1_kernel(const unsigned short* __restrict__ gh,
                                                    float* __restrict__ cA,
                                                    float* __restrict__ cV) {
    int b = blockIdx.x >> 7, c = blockIdx.x & 127;
    int h = threadIdx.x * 4;
    const unsigned short* base = gh + ((size_t)(b * NT + c * CTS)) * NN + h;
    float A0 = 1.f, A1 = 1.f, A2 = 1.f, A3 = 1.f;
    float V0 = 0.f, V1 = 0.f, V2 = 0.f, V3 = 0.f;
#pragma unroll 1
    for (int tb = 0; tb < CTS; tb += 8) {
        ushort4 kb[8], hb[8];
#pragma unroll
        for (int j = 0; j < 8; ++j) {
            const unsigned short* p = base + (size_t)(tb + j) * NN;
            kb[j] = *(const ushort4*)p;
            hb[j] = *(const ushort4*)(p + NH);
        }
#pragma unroll
        for (int j = 0; j < 8; ++j) {
            float a, v;
            gate_av(kb[j].x, hb[j].x, a, v); V0 = a * V0 + v; A0 *= a;
            gate_av(kb[j].y, hb[j].y, a, v); V1 = a * V1 + v; A1 *= a;
            gate_av(kb[j].z, hb[j].z, a, v); V2 = a * V2 + v; A2 *= a;
            gate_av(kb[j].w, hb[j].w, a, v); V3 = a * V3 + v; A3 *= a;
        }
    }
    size_t o = ((size_t)b * NH + h) * NCH + c;
    cA[o] = A0; cA[o + NCH] = A1; cA[o + 2 * NCH] = A2; cA[o + 3 * NCH] = A3;
    cV[o] = V0; cV[o + NCH] = V1; cV[o + 2 * NCH] = V2; cV[o + 3 * NCH] = V3;
}

// ---------------- Kernel 4: scan over chunk aggregates --------------------
// one wave per (b,h) channel; lane handles 2 consecutive chunks (float2).
__global__ __launch_bounds__(256) void scan2_kernel(const float* __restrict__ cA,
                                                    const float* __restrict__ cV,
                                                    float* __restrict__ hinit) {
    int w = blockIdx.x * 4 + (threadIdx.x >> 6);  // 0..4095 = channel
    int lane = threadIdx.x & 63;
    int b = w >> 9, h = w & 511;
    const float2* a2p = (const float2*)(cA + ((size_t)b * NH + h) * NCH);
    const float2* v2p = (const float2*)(cV + ((size_t)b * NH + h) * NCH);
    float2 a2 = a2p[lane];
    float2 v2 = v2p[lane];
    // compose the lane's two chunks (apply chunk 2l, then 2l+1)
    float A = a2.y * a2.x;
    float V = a2.y * v2.x + v2.y;
#pragma unroll
    for (int off = 1; off < 64; off <<= 1) {
        float Ap = __shfl_up(A, off, 64);
        float Vp = __shfl_up(V, off, 64);
        if (lane >= off) { V = A * Vp + V; A = A * Ap; }
    }
    float excl = __shfl_up(V, 1, 64);
    if (lane == 0) excl = 0.f;
    float e0 = excl;               // h entering chunk 2*lane
    float e1 = a2.x * e0 + v2.x;   // h entering chunk 2*lane+1
    hinit[((size_t)b * NCH + 2 * lane) * NH + h]     = e0;
    hinit[((size_t)b * NCH + 2 * lane + 1) * NH + h] = e1;
}

// ---------------- Kernel 5: replay chunks, write out & hidden -------------
// Same 8-deep load batching (kb/hb/xv = 32 loads in flight incl. 16B x).
__global__ __launch_bounds__(128) void scan3_kernel(const unsigned short* __restrict__ gh,
                                                    const float* __restrict__ hinit,
                                                    const float* __restrict__ x,
                                                    float* __restrict__ out,
                                                    float* __restrict__ hidden) {
    int b = blockIdx.x >> 7, c = blockIdx.x & 127;
    int h = threadIdx.x * 4;
    size_t row0 = (size_t)(b * NT + c * CTS);
    const unsigned short* base = gh + row0 * NN + h;
    const float* xb = x + row0 * ND + h;
    float* ob = out + row0 * ND + h;
    float4 hv = *(const float4*)(hinit + ((size_t)b * NCH + c) * NH + h);
#pragma unroll 1
    for (int tb = 0; tb < CTS; tb += 8) {
        ushort4 kb[8], hb[8];
        float4 xv[8];
#pragma unroll
        for (int j = 0; j < 8; ++j) {
            const unsigned short* p = base + (size_t)(tb + j) * NN;
            kb[j] = *(const ushort4*)p;
            hb[j] = *(const ushort4*)(p + NH);
            xv[j] = *(const float4*)(xb + (size_t)(tb + j) * ND);
        }
#pragma unroll
        for (int j = 0; j < 8; ++j) {
            float a, v;
            gate_av(kb[j].x, hb[j].x, a, v); hv.x = a * hv.x + v;
            gate_av(kb[j].y, hb[j].y, a, v); hv.y = a * hv.y + v;
            gate_av(kb[j].z, hb[j].z, a, v); hv.z = a * hv.z + v;
            gate_av(kb[j].w, hb[j].w, a, v); hv.w = a * hv.w + v;
            float4 ov;
            ov.x = hv.x + xv[j].x; ov.y = hv.y + xv[j].y;
            ov.z = hv.z + xv[j].z; ov.w = hv.w + xv[j].w;
            *(float4*)(ob + (size_t)(tb + j) * ND) = ov;
        }
    }
    if (c == NCH - 1)
        *(float4*)(hidden + (size_t)b * NH + h) = hv;
}

extern "C" void kernel_launch(void* const* d_in, const int* in_sizes, int n_in,
                              void* d_out, int out_size, void* d_ws, size_t ws_size,
                              hipStream_t stream) {
    const float* x     = (const float*)d_in[0];
    const float* gamma = (const float*)d_in[1];
    const float* beta  = (const float*)d_in[2];
    const float* W     = (const float*)d_in[3];

    float* out    = (float*)d_out;
    float* hidden = out + (size_t)NM * ND;

    // ws layout: Wt(1MB) | gh(64MB) | cA(2MB) | cV(2MB) | hinit(2MB) = 71MB
    char* ws = (char*)d_ws;
    unsigned short* Wt = (unsigned short*)ws;
    unsigned short* gh = (unsigned short*)(ws + (size_t)(1u << 20));
    float* cA    = (float*)(ws + (size_t)(1u << 20) + (size_t)NM * NN * 2);
    float* cV    = cA + (size_t)NB * NCH * NH;
    float* hinit = cV + (size_t)NB * NCH * NH;
    // xn scratch lives in d_out (dead before scan3 overwrites the region)
    unsigned short* xn = (unsigned short*)d_out;

    prep_kernel<<<512 + NM / 4, 256, 0, stream>>>(x, gamma, beta, W, xn, Wt);
    gemm_kernel<<<2048, 256, 0, stream>>>(xn, Wt, gh);
    scan1_kernel<<<NB * NCH, 128, 0, stream>>>(gh, cA, cV);
    scan2_kernel<<<1024, 256, 0, stream>>>(cA, cV, hinit);
    scan3_kernel<<<NB * NCH, 128, 0, stream>>>(gh, hinit, x, out, hidden);
}